// Round 9
// baseline (16.966 us; speedup 1.0000x reference)
//
#include <hip/hip_runtime.h>

#define X_DIM 5
#define Y_DIM 2
#define H1 560
#define H2 40
#define GRUH 145
#define G3 435
#define NB_H0 37          // K1 h0 blocks (37*4 waves = 148 >= 145)
#define NB_GH1 109        // K1 gh1 blocks (109*4 = 436 >= 435)
#define NB_K2 37

__device__ __forceinline__ float wave_reduce(float v) {
#pragma unroll
    for (int off = 32; off > 0; off >>= 1)
        v += __shfl_xor(v, off, 64);
    return v;
}
__device__ __forceinline__ float sigmoidf_(float x) { return 1.0f / (1.0f + __expf(-x)); }
__device__ __forceinline__ float dot4(float4 a, float4 b) {
    return fmaf(a.x, b.x, fmaf(a.y, b.y, fmaf(a.z, b.z, a.w * b.w)));
}

// K1: blocks [0,37): wave-per-h0-element, R8-style single-epoch l1 + full
//     prefetch before one __syncthreads. blocks [37,146): gh1 rows, direct
//     global reads, zero LDS/sync (R7-style). Block 37 resets the K2 counter.
__global__ __launch_bounds__(256) void k1_gru0(
    const float* __restrict__ si, const float* __restrict__ oi,
    const float* __restrict__ dst, const float* __restrict__ dob,
    const float* __restrict__ W1, const float* __restrict__ b1,
    const float* __restrict__ Wih0, const float* __restrict__ Whh0,
    const float* __restrict__ bih0, const float* __restrict__ bhh0,
    const float* __restrict__ Whh1, const float* __restrict__ bhh1,
    const float* __restrict__ hn,
    unsigned* __restrict__ ctr,
    float* __restrict__ h0g, float* __restrict__ gh1g)
{
    const int tid = threadIdx.x;
    const int wid = tid >> 6, lane = tid & 63;
    const bool t3 = (lane < 17);    // 145 = 64+64+17

    if (blockIdx.x >= NB_H0) {
        // ---- gh1 rows: no LDS, no sync ----
        if (blockIdx.x == NB_H0 && tid == 0)
            __hip_atomic_store(ctr, 0u, __ATOMIC_RELAXED, __HIP_MEMORY_SCOPE_AGENT);
        const int r   = (blockIdx.x - NB_H0) * 4 + wid;
        const bool act = (r < G3);
        const int rr  = act ? r : (G3 - 1);
        const float* rp = Whh1 + rr * GRUH;
        const float wa = rp[lane], wb = rp[lane + 64], wc = t3 ? rp[lane + 128] : 0.f;
        const float ha = hn[GRUH + lane], hb = hn[GRUH + lane + 64],
                    hc = t3 ? hn[GRUH + lane + 128] : 0.f;
        const float bb = bhh1[rr];
        float a = fmaf(wa, ha, fmaf(wb, hb, wc * hc));
        a = wave_reduce(a);
        if (lane == 0 && act) gh1g[r] = a + bb;
        return;
    }

    __shared__ __align__(16) float sl1[H1];
    const bool f3 = (lane < 12);    // 140 float4 = 64+64+12
    const float4 z4 = make_float4(0.f, 0.f, 0.f, 0.f);

    const int e   = blockIdx.x * 4 + wid;
    const bool act = (e < GRUH);
    const int ee  = act ? e : (GRUH - 1);

    // ---- prefetch: Wih0 rows (float4), Whh0 rows, hn0, biases ----
    const float4* p0 = reinterpret_cast<const float4*>(Wih0 + (ee           ) * H1);
    const float4* p1 = reinterpret_cast<const float4*>(Wih0 + (ee +   GRUH  ) * H1);
    const float4* p2 = reinterpret_cast<const float4*>(Wih0 + (ee + 2 * GRUH) * H1);
    const float4 q00 = p0[lane], q01 = p0[lane + 64], q02 = f3 ? p0[lane + 128] : z4;
    const float4 q10 = p1[lane], q11 = p1[lane + 64], q12 = f3 ? p1[lane + 128] : z4;
    const float4 q20 = p2[lane], q21 = p2[lane + 64], q22 = f3 ? p2[lane + 128] : z4;
    const float* wr0 = Whh0 + (ee           ) * GRUH;
    const float* wr1 = Whh0 + (ee +   GRUH  ) * GRUH;
    const float* wr2 = Whh0 + (ee + 2 * GRUH) * GRUH;
    const float w00 = wr0[lane], w01 = wr0[lane + 64], w02 = t3 ? wr0[lane + 128] : 0.f;
    const float w10 = wr1[lane], w11 = wr1[lane + 64], w12 = t3 ? wr1[lane + 128] : 0.f;
    const float w20 = wr2[lane], w21 = wr2[lane + 64], w22 = t3 ? wr2[lane + 128] : 0.f;
    const float ha = hn[lane], hb = hn[lane + 64], hc = t3 ? hn[lane + 128] : 0.f;
    const float bi0 = bih0[ee], bi1 = bih0[ee + GRUH], bi2 = bih0[ee + 2 * GRUH];
    const float bh0 = bhh0[ee], bh1 = bhh0[ee + GRUH], bh2 = bhh0[ee + 2 * GRUH];
    const float hne = hn[ee];

    // ---- x into regs (vectorized broadcast) ----
    const float4 s4 = *reinterpret_cast<const float4*>(si);
    const float  s5 = si[4];
    const float2 o2 = *reinterpret_cast<const float2*>(oi);
    const float4 d4 = *reinterpret_cast<const float4*>(dst);
    const float  d5 = dst[4];
    const float2 e2 = *reinterpret_cast<const float2*>(dob);
    float x[14] = { s4.x, s4.y, s4.z, s4.w, s5, o2.x, o2.y,
                    d4.x, d4.y, d4.z, d4.w, d5, e2.x, e2.y };

    // ---- l1 rows j0,j1 (all threads) and j2 (tid<48): ONE load epoch ----
    const int j0 = tid, j1 = tid + 256, j2 = tid + 512;
    const bool has2 = (j2 < H1);
    float2 A[7], B[7], C[7];
    const float2* w1p0 = reinterpret_cast<const float2*>(W1 + j0 * 14);
    const float2* w1p1 = reinterpret_cast<const float2*>(W1 + j1 * 14);
    const float2* w1p2 = reinterpret_cast<const float2*>(W1 + (has2 ? j2 : j0) * 14);
#pragma unroll
    for (int k = 0; k < 7; ++k) { A[k] = w1p0[k]; B[k] = w1p1[k]; C[k] = w1p2[k]; }
    const float bb0 = b1[j0], bb1_ = b1[j1], bb2_ = b1[has2 ? j2 : j0];
    float a0_ = bb0, a1_ = bb1_, a2_ = bb2_;
#pragma unroll
    for (int k = 0; k < 7; ++k) {
        a0_ = fmaf(A[k].x, x[2 * k], fmaf(A[k].y, x[2 * k + 1], a0_));
        a1_ = fmaf(B[k].x, x[2 * k], fmaf(B[k].y, x[2 * k + 1], a1_));
        a2_ = fmaf(C[k].x, x[2 * k], fmaf(C[k].y, x[2 * k + 1], a2_));
    }
    sl1[j0] = fmaxf(a0_, 0.0f);
    sl1[j1] = fmaxf(a1_, 0.0f);
    if (has2) sl1[j2] = fmaxf(a2_, 0.0f);
    __syncthreads();

    // ---- gi0 (prefetched regs x LDS float4) + gh0 (pure regs) ----
    const float4 s0 = *reinterpret_cast<const float4*>(&sl1[4 * lane]);
    const float4 s1 = *reinterpret_cast<const float4*>(&sl1[4 * (lane + 64)]);
    const float4 s2 = f3 ? *reinterpret_cast<const float4*>(&sl1[4 * (lane + 128)]) : z4;
    float a0 = dot4(q00, s0) + dot4(q01, s1) + dot4(q02, s2);
    float a1 = dot4(q10, s0) + dot4(q11, s1) + dot4(q12, s2);
    float a2 = dot4(q20, s0) + dot4(q21, s1) + dot4(q22, s2);
    float a3 = fmaf(w00, ha, fmaf(w01, hb, w02 * hc));
    float a4 = fmaf(w10, ha, fmaf(w11, hb, w12 * hc));
    float a5 = fmaf(w20, ha, fmaf(w21, hb, w22 * hc));
    a0 = wave_reduce(a0); a1 = wave_reduce(a1); a2 = wave_reduce(a2);
    a3 = wave_reduce(a3); a4 = wave_reduce(a4); a5 = wave_reduce(a5);
    if (lane == 0 && act) {
        const float r = sigmoidf_(a0 + bi0 + a3 + bh0);
        const float z = sigmoidf_(a1 + bi1 + a4 + bh1);
        const float n = tanhf   (a2 + bi2 + r * (a5 + bh2));
        h0g[e] = (1.0f - z) * n + z * hne;
    }
}

// K2: minimal dependent work only. Wave-per-element: 3 Wih1 dots over h0g
// (direct coalesced reads) + precomputed gh1g (3 broadcast loads), gates,
// RELEASE store; one fetch_add; all-block W2 prefetch; last block runs head.
__global__ __launch_bounds__(256) void k2_gru1_head(
    const float* __restrict__ Wih1, const float* __restrict__ bih1,
    const float* __restrict__ W2a, const float* __restrict__ b2a,
    const float* __restrict__ W2b, const float* __restrict__ b2b,
    const float* __restrict__ hn,
    const float* __restrict__ h0g, const float* __restrict__ gh1g,
    unsigned* __restrict__ ctr,
    float* __restrict__ h1g, float* __restrict__ out)
{
    __shared__ float sh1[GRUH];
    __shared__ float sl2h[H2];
    __shared__ unsigned slast;

    const int tid = threadIdx.x;
    const int wid = tid >> 6, lane = tid & 63;
    const bool t3 = (lane < 17);
    const int e   = blockIdx.x * 4 + wid;
    const bool act = (e < GRUH);
    const int ee  = act ? e : (GRUH - 1);

    // ---- one epoch: Wih1 rows + gh1 + biases + hn1[e] + h0 ----
    const float* r0 = Wih1 + (ee           ) * GRUH;
    const float* r1 = Wih1 + (ee +   GRUH  ) * GRUH;
    const float* r2 = Wih1 + (ee + 2 * GRUH) * GRUH;
    const float w0a = r0[lane], w0b = r0[lane + 64], w0c = t3 ? r0[lane + 128] : 0.f;
    const float w1a = r1[lane], w1b = r1[lane + 64], w1c = t3 ? r1[lane + 128] : 0.f;
    const float w2a = r2[lane], w2b = r2[lane + 64], w2c = t3 ? r2[lane + 128] : 0.f;
    const float g0 = gh1g[ee], g1 = gh1g[ee + GRUH], g2 = gh1g[ee + 2 * GRUH];
    const float bi0 = bih1[ee], bi1 = bih1[ee + GRUH], bi2 = bih1[ee + 2 * GRUH];
    const float hn1e = hn[GRUH + ee];
    const float x0 = h0g[lane], x1 = h0g[lane + 64], x2 = t3 ? h0g[lane + 128] : 0.f;

    float c0 = fmaf(w0a, x0, fmaf(w0b, x1, w0c * x2));
    float c1 = fmaf(w1a, x0, fmaf(w1b, x1, w1c * x2));
    float c2 = fmaf(w2a, x0, fmaf(w2b, x1, w2c * x2));
    c0 = wave_reduce(c0); c1 = wave_reduce(c1); c2 = wave_reduce(c2);
    if (lane == 0 && act) {
        const float r = sigmoidf_(c0 + bi0 + g0);
        const float z = sigmoidf_(c1 + bi1 + g1);
        const float n = tanhf   (c2 + bi2 + r * g2);
        const float v = (1.0f - z) * n + z * hn1e;
        __hip_atomic_store(&h1g[e], v, __ATOMIC_RELEASE, __HIP_MEMORY_SCOPE_AGENT);
    }
    __syncthreads();
    if (tid == 0) {
        const unsigned old =
            __hip_atomic_fetch_add(ctr, 1u, __ATOMIC_ACQ_REL, __HIP_MEMORY_SCOPE_AGENT);
        slast = (old == NB_K2 - 1u) ? 1u : 0u;
    }

    // ---- head-weight prefetch (in flight while slast resolves) ----
    float wa[10][3];
    const int rbase = wid * 10;
#pragma unroll
    for (int m = 0; m < 10; ++m) {
        const float* rp = W2a + (rbase + m) * GRUH;
        wa[m][0] = rp[lane];
        wa[m][1] = rp[lane + 64];
        wa[m][2] = t3 ? rp[lane + 128] : 0.f;
    }
    float ba[10];
#pragma unroll
    for (int m = 0; m < 10; ++m) ba[m] = b2a[rbase + m];
    float wb2[H2], bb2 = 0.f;
    if (tid < X_DIM * Y_DIM) {
        const float* rp = W2b + tid * H2;
#pragma unroll
        for (int k = 0; k < H2; ++k) wb2[k] = rp[k];
        bb2 = b2b[tid];
    }

    __syncthreads();
    if (!slast) return;

    // ---- last block only: stage h1 (acquire) and run the head ----
    for (int j = tid; j < GRUH; j += 256)
        sh1[j] = __hip_atomic_load(&h1g[j], __ATOMIC_ACQUIRE, __HIP_MEMORY_SCOPE_AGENT);
    __syncthreads();

    const float za = sh1[lane], zb = sh1[lane + 64], zc = t3 ? sh1[lane + 128] : 0.f;
#pragma unroll
    for (int m = 0; m < 10; ++m) {
        float a = fmaf(wa[m][0], za, fmaf(wa[m][1], zb, wa[m][2] * zc));
        a = wave_reduce(a);
        if (lane == 0) sl2h[rbase + m] = fmaxf(a + ba[m], 0.0f);
    }
    __syncthreads();
    if (tid < X_DIM * Y_DIM) {
        float a = bb2;
#pragma unroll
        for (int k = 0; k < H2; ++k) a = fmaf(wb2[k], sl2h[k], a);
        out[tid] = a;
    }
}

extern "C" void kernel_launch(void* const* d_in, const int* in_sizes, int n_in,
                              void* d_out, int out_size, void* d_ws, size_t ws_size,
                              hipStream_t stream) {
    const float* si   = (const float*)d_in[0];
    const float* oi   = (const float*)d_in[1];
    const float* dst  = (const float*)d_in[2];
    const float* dob  = (const float*)d_in[3];
    const float* W1   = (const float*)d_in[4];
    const float* b1   = (const float*)d_in[5];
    const float* Wih0 = (const float*)d_in[6];
    const float* Whh0 = (const float*)d_in[7];
    const float* bih0 = (const float*)d_in[8];
    const float* bhh0 = (const float*)d_in[9];
    const float* Wih1 = (const float*)d_in[10];
    const float* Whh1 = (const float*)d_in[11];
    const float* bih1 = (const float*)d_in[12];
    const float* bhh1 = (const float*)d_in[13];
    const float* W2a  = (const float*)d_in[14];
    const float* b2a  = (const float*)d_in[15];
    const float* W2b  = (const float*)d_in[16];
    const float* b2b  = (const float*)d_in[17];
    const float* hn   = (const float*)d_in[18];

    float* ws = (float*)d_ws;
    unsigned* ctr = (unsigned*)d_ws;   // 1 cache line
    float* h0g  = ws + 64;             // 145 floats
    float* gh1g = ws + 64 + 256;       // 435 floats
    float* h1g  = ws + 64 + 256 + 512; // 145 floats

    hipLaunchKernelGGL(k1_gru0, dim3(NB_H0 + NB_GH1), dim3(256), 0, stream,
                       si, oi, dst, dob, W1, b1, Wih0, Whh0, bih0, bhh0,
                       Whh1, bhh1, hn, ctr, h0g, gh1g);
    hipLaunchKernelGGL(k2_gru1_head, dim3(NB_K2), dim3(256), 0, stream,
                       Wih1, bih1, W2a, b2a, W2b, b2b, hn, h0g, gh1g,
                       ctr, h1g, (float*)d_out);
}

// Round 10
// 15.482 us; speedup vs baseline: 1.0959x; 1.0959x over previous
//
#include <hip/hip_runtime.h>

#define X_DIM 5
#define Y_DIM 2
#define H1 560
#define H2 40
#define GRUH 145
#define G3 435
#define NB_H0 37          // K1 h0 blocks
#define NB_GH1 109        // K1 gh1 blocks (109*4 = 436 >= 435)
#define NB_K2 19          // K2 blocks: 19 x 8 waves = 152 >= 145

__device__ __forceinline__ float wave_reduce(float v) {
#pragma unroll
    for (int off = 32; off > 0; off >>= 1)
        v += __shfl_xor(v, off, 64);
    return v;
}
__device__ __forceinline__ float sigmoidf_(float x) { return 1.0f / (1.0f + __expf(-x)); }
__device__ __forceinline__ float dot4(float4 a, float4 b) {
    return fmaf(a.x, b.x, fmaf(a.y, b.y, fmaf(a.z, b.z, a.w * b.w)));
}

// K1 (R6 verbatim): blocks [0,37): wave-per-h0-element, full prefetch before
// one __syncthreads; blocks [37,146): gh1 rows. Block 37 resets K2 counter.
__global__ __launch_bounds__(256) void k1_gru0(
    const float* __restrict__ si, const float* __restrict__ oi,
    const float* __restrict__ dst, const float* __restrict__ dob,
    const float* __restrict__ W1, const float* __restrict__ b1,
    const float* __restrict__ Wih0, const float* __restrict__ Whh0,
    const float* __restrict__ bih0, const float* __restrict__ bhh0,
    const float* __restrict__ Whh1, const float* __restrict__ bhh1,
    const float* __restrict__ hn,
    unsigned* __restrict__ ctr,
    float* __restrict__ h0g, float* __restrict__ gh1g)
{
    const int tid = threadIdx.x;
    const int wid = tid >> 6, lane = tid & 63;
    const bool t3 = (lane < 17);    // 145 = 64+64+17

    if (blockIdx.x < NB_H0) {
        __shared__ __align__(16) float sl1[H1];
        const bool f3 = (lane < 12);             // 140 float4 = 64+64+12
        const float4 z4 = make_float4(0.f, 0.f, 0.f, 0.f);
        const int e   = blockIdx.x * 4 + wid;
        const bool act = (e < GRUH);
        const int ee  = act ? e : (GRUH - 1);

        // ---- prefetch: Whh0 rows + hn0 (gh0 path, reg-only) ----
        const float* wr0 = Whh0 + (ee           ) * GRUH;
        const float* wr1 = Whh0 + (ee +   GRUH  ) * GRUH;
        const float* wr2 = Whh0 + (ee + 2 * GRUH) * GRUH;
        const float h_a = hn[lane], h_b = hn[lane + 64], h_c = t3 ? hn[lane + 128] : 0.f;
        const float w00 = wr0[lane], w01 = wr0[lane + 64], w02 = t3 ? wr0[lane + 128] : 0.f;
        const float w10 = wr1[lane], w11 = wr1[lane + 64], w12 = t3 ? wr1[lane + 128] : 0.f;
        const float w20 = wr2[lane], w21 = wr2[lane + 64], w22 = t3 ? wr2[lane + 128] : 0.f;

        // ---- prefetch: Wih0 rows as float4 ----
        const float4* p0 = reinterpret_cast<const float4*>(Wih0 + (ee           ) * H1);
        const float4* p1 = reinterpret_cast<const float4*>(Wih0 + (ee +   GRUH  ) * H1);
        const float4* p2 = reinterpret_cast<const float4*>(Wih0 + (ee + 2 * GRUH) * H1);
        const float4 q00 = p0[lane], q01 = p0[lane + 64], q02 = f3 ? p0[lane + 128] : z4;
        const float4 q10 = p1[lane], q11 = p1[lane + 64], q12 = f3 ? p1[lane + 128] : z4;
        const float4 q20 = p2[lane], q21 = p2[lane + 64], q22 = f3 ? p2[lane + 128] : z4;

        // ---- prefetch: biases + hn[e] ----
        const float bi0 = bih0[ee], bi1 = bih0[ee + GRUH], bi2 = bih0[ee + 2 * GRUH];
        const float bh0 = bhh0[ee], bh1 = bhh0[ee + GRUH], bh2 = bhh0[ee + 2 * GRUH];
        const float hne = hn[ee];

        // ---- x into regs ----
        float x[14];
#pragma unroll
        for (int k = 0; k < 5; ++k) x[k] = si[k];
        x[5] = oi[0]; x[6] = oi[1];
#pragma unroll
        for (int k = 0; k < 5; ++k) x[7 + k] = dst[k];
        x[12] = dob[0]; x[13] = dob[1];

        // ---- l1 = relu(W1 @ x + b1) -> LDS ----
        for (int j = tid; j < H1; j += 256) {
            float a = b1[j];
            const float* wp = W1 + j * 14;
#pragma unroll
            for (int k = 0; k < 14; ++k) a = fmaf(wp[k], x[k], a);
            sl1[j] = fmaxf(a, 0.0f);
        }

        // ---- gh0 (pure registers, overlaps l1) ----
        float a3 = fmaf(w00, h_a, fmaf(w01, h_b, w02 * h_c));
        float a4 = fmaf(w10, h_a, fmaf(w11, h_b, w12 * h_c));
        float a5 = fmaf(w20, h_a, fmaf(w21, h_b, w22 * h_c));

        __syncthreads();

        // ---- gi0 from prefetched regs x LDS float4 ----
        const float4 s0 = *reinterpret_cast<const float4*>(&sl1[4 * lane]);
        const float4 s1 = *reinterpret_cast<const float4*>(&sl1[4 * (lane + 64)]);
        const float4 s2 = f3 ? *reinterpret_cast<const float4*>(&sl1[4 * (lane + 128)]) : z4;
        float a0 = dot4(q00, s0) + dot4(q01, s1) + dot4(q02, s2);
        float a1 = dot4(q10, s0) + dot4(q11, s1) + dot4(q12, s2);
        float a2 = dot4(q20, s0) + dot4(q21, s1) + dot4(q22, s2);

        a0 = wave_reduce(a0); a1 = wave_reduce(a1); a2 = wave_reduce(a2);
        a3 = wave_reduce(a3); a4 = wave_reduce(a4); a5 = wave_reduce(a5);
        if (lane == 0 && act) {
            const float r = sigmoidf_(a0 + bi0 + a3 + bh0);
            const float z = sigmoidf_(a1 + bi1 + a4 + bh1);
            const float n = tanhf   (a2 + bi2 + r * (a5 + bh2));
            h0g[e] = (1.0f - z) * n + z * hne;
        }
    } else {
        if (blockIdx.x == NB_H0 && tid == 0)
            __hip_atomic_store(ctr, 0u, __ATOMIC_RELAXED, __HIP_MEMORY_SCOPE_AGENT);
        const int r   = (blockIdx.x - NB_H0) * 4 + wid;
        const bool act = (r < G3);
        const int rr  = act ? r : (G3 - 1);
        const float* rp = Whh1 + rr * GRUH;
        const float wa = rp[lane], wb = rp[lane + 64], wc = t3 ? rp[lane + 128] : 0.f;
        const float ha = hn[GRUH + lane], hb = hn[GRUH + lane + 64],
                    hc = t3 ? hn[GRUH + lane + 128] : 0.f;
        const float bb = bhh1[rr];
        float a = fmaf(wa, ha, fmaf(wb, hb, wc * hc));
        a = wave_reduce(a);
        if (lane == 0 && act) gh1g[r] = a + bb;
    }
}

// K2: 19 blocks x 512 (8 waves, wave-per-element) — HALF the gate RMWs vs 37.
// Same skeleton as R6: release-stores, one fetch_add, all-block W2 prefetch,
// non-spinning last-block head.
__global__ __launch_bounds__(512) void k2_gru1_head(
    const float* __restrict__ Wih1, const float* __restrict__ bih1,
    const float* __restrict__ W2a, const float* __restrict__ b2a,
    const float* __restrict__ W2b, const float* __restrict__ b2b,
    const float* __restrict__ hn,
    const float* __restrict__ h0g, const float* __restrict__ gh1g,
    unsigned* __restrict__ ctr,
    float* __restrict__ h1g, float* __restrict__ out)
{
    __shared__ float sh1[GRUH];
    __shared__ float sl2h[H2];
    __shared__ unsigned slast;

    const int tid = threadIdx.x;
    const int wid = tid >> 6, lane = tid & 63;   // wid 0..7
    const bool t3 = (lane < 17);
    const int e   = blockIdx.x * 8 + wid;
    const bool act = (e < GRUH);
    const int ee  = act ? e : (GRUH - 1);

    // ---- one epoch: Wih1 rows + gh1 + biases + hn1[e] + h0 ----
    const float* r0 = Wih1 + (ee           ) * GRUH;
    const float* r1 = Wih1 + (ee +   GRUH  ) * GRUH;
    const float* r2 = Wih1 + (ee + 2 * GRUH) * GRUH;
    const float w0a = r0[lane], w0b = r0[lane + 64], w0c = t3 ? r0[lane + 128] : 0.f;
    const float w1a = r1[lane], w1b = r1[lane + 64], w1c = t3 ? r1[lane + 128] : 0.f;
    const float w2a = r2[lane], w2b = r2[lane + 64], w2c = t3 ? r2[lane + 128] : 0.f;
    const float g0 = gh1g[ee], g1 = gh1g[ee + GRUH], g2 = gh1g[ee + 2 * GRUH];
    const float bi0 = bih1[ee], bi1 = bih1[ee + GRUH], bi2 = bih1[ee + 2 * GRUH];
    const float hn1e = hn[GRUH + ee];
    const float x0 = h0g[lane], x1 = h0g[lane + 64], x2 = t3 ? h0g[lane + 128] : 0.f;

    float c0 = fmaf(w0a, x0, fmaf(w0b, x1, w0c * x2));
    float c1 = fmaf(w1a, x0, fmaf(w1b, x1, w1c * x2));
    float c2 = fmaf(w2a, x0, fmaf(w2b, x1, w2c * x2));
    c0 = wave_reduce(c0); c1 = wave_reduce(c1); c2 = wave_reduce(c2);
    if (lane == 0 && act) {
        const float r = sigmoidf_(c0 + bi0 + g0);
        const float z = sigmoidf_(c1 + bi1 + g1);
        const float n = tanhf   (c2 + bi2 + r * g2);
        const float v = (1.0f - z) * n + z * hn1e;
        __hip_atomic_store(&h1g[e], v, __ATOMIC_RELEASE, __HIP_MEMORY_SCOPE_AGENT);
    }
    __syncthreads();
    if (tid == 0) {
        const unsigned old =
            __hip_atomic_fetch_add(ctr, 1u, __ATOMIC_ACQ_REL, __HIP_MEMORY_SCOPE_AGENT);
        slast = (old == NB_K2 - 1u) ? 1u : 0u;
    }

    // ---- head-weight prefetch (in flight while slast resolves) ----
    float wa[5][3];
    const int rbase = wid * 5;                   // 8 waves x 5 rows = 40
#pragma unroll
    for (int m = 0; m < 5; ++m) {
        const float* rp = W2a + (rbase + m) * GRUH;
        wa[m][0] = rp[lane];
        wa[m][1] = rp[lane + 64];
        wa[m][2] = t3 ? rp[lane + 128] : 0.f;
    }
    float ba[5];
#pragma unroll
    for (int m = 0; m < 5; ++m) ba[m] = b2a[rbase + m];
    float wb2[H2], bb2 = 0.f;
    if (tid < X_DIM * Y_DIM) {
        const float* rp = W2b + tid * H2;
#pragma unroll
        for (int k = 0; k < H2; ++k) wb2[k] = rp[k];
        bb2 = b2b[tid];
    }

    __syncthreads();
    if (!slast) return;

    // ---- last block only: stage h1 (acquire) and run the head ----
    for (int j = tid; j < GRUH; j += 512)
        sh1[j] = __hip_atomic_load(&h1g[j], __ATOMIC_ACQUIRE, __HIP_MEMORY_SCOPE_AGENT);
    __syncthreads();

    const float za = sh1[lane], zb = sh1[lane + 64], zc = t3 ? sh1[lane + 128] : 0.f;
#pragma unroll
    for (int m = 0; m < 5; ++m) {
        float a = fmaf(wa[m][0], za, fmaf(wa[m][1], zb, wa[m][2] * zc));
        a = wave_reduce(a);
        if (lane == 0) sl2h[rbase + m] = fmaxf(a + ba[m], 0.0f);
    }
    __syncthreads();
    if (tid < X_DIM * Y_DIM) {
        float a = bb2;
#pragma unroll
        for (int k = 0; k < H2; ++k) a = fmaf(wb2[k], sl2h[k], a);
        out[tid] = a;
    }
}

extern "C" void kernel_launch(void* const* d_in, const int* in_sizes, int n_in,
                              void* d_out, int out_size, void* d_ws, size_t ws_size,
                              hipStream_t stream) {
    const float* si   = (const float*)d_in[0];
    const float* oi   = (const float*)d_in[1];
    const float* dst  = (const float*)d_in[2];
    const float* dob  = (const float*)d_in[3];
    const float* W1   = (const float*)d_in[4];
    const float* b1   = (const float*)d_in[5];
    const float* Wih0 = (const float*)d_in[6];
    const float* Whh0 = (const float*)d_in[7];
    const float* bih0 = (const float*)d_in[8];
    const float* bhh0 = (const float*)d_in[9];
    const float* Wih1 = (const float*)d_in[10];
    const float* Whh1 = (const float*)d_in[11];
    const float* bih1 = (const float*)d_in[12];
    const float* bhh1 = (const float*)d_in[13];
    const float* W2a  = (const float*)d_in[14];
    const float* b2a  = (const float*)d_in[15];
    const float* W2b  = (const float*)d_in[16];
    const float* b2b  = (const float*)d_in[17];
    const float* hn   = (const float*)d_in[18];

    float* ws = (float*)d_ws;
    unsigned* ctr = (unsigned*)d_ws;   // 1 cache line
    float* h0g  = ws + 64;             // 145 floats
    float* gh1g = ws + 64 + 256;       // 435 floats
    float* h1g  = ws + 64 + 256 + 512; // 145 floats

    hipLaunchKernelGGL(k1_gru0, dim3(NB_H0 + NB_GH1), dim3(256), 0, stream,
                       si, oi, dst, dob, W1, b1, Wih0, Whh0, bih0, bhh0,
                       Whh1, bhh1, hn, ctr, h0g, gh1g);
    hipLaunchKernelGGL(k2_gru1_head, dim3(NB_K2), dim3(512), 0, stream,
                       Wih1, bih1, W2a, b2a, W2b, b2b, hn, h0g, gh1g,
                       ctr, h1g, (float*)d_out);
}